// Round 1
// baseline (370.832 us; speedup 1.0000x reference)
//
#include <hip/hip_runtime.h>
#include <hip/hip_bf16.h>
#include <math.h>

typedef __bf16 bf16_t;
typedef __bf16 bf16x8 __attribute__((ext_vector_type(8)));
typedef float f32x4 __attribute__((ext_vector_type(4)));

__device__ __forceinline__ void gload_lds16(const void* g, void* l) {
  __builtin_amdgcn_global_load_lds((const __attribute__((address_space(1))) void*)g,
                                   (__attribute__((address_space(3))) void*)l, 16, 0, 0);
}

// ---------------- cast fp32 -> bf16 (vectorized x8) ----------------
__global__ void castk(const float* __restrict__ in, bf16_t* __restrict__ out, int n) {
  int i = (blockIdx.x * blockDim.x + threadIdx.x) * 8;
  if (i >= n) return;
  float4 a = *(const float4*)(in + i);
  float4 b = *(const float4*)(in + i + 4);
  bf16x8 o;
  o[0] = (bf16_t)a.x; o[1] = (bf16_t)a.y; o[2] = (bf16_t)a.z; o[3] = (bf16_t)a.w;
  o[4] = (bf16_t)b.x; o[5] = (bf16_t)b.y; o[6] = (bf16_t)b.z; o[7] = (bf16_t)b.w;
  *(bf16x8*)(out + i) = o;
}

// ------------- transpose + cast: in fp32 [K][N] -> out bf16 [N][K] -------------
__global__ void transk(const float* __restrict__ in, bf16_t* __restrict__ out,
                       int K, int N) {
  __shared__ float t[32][33];
  int n0 = blockIdx.x * 32, k0 = blockIdx.y * 32;
  int tx = threadIdx.x & 31, ty = threadIdx.x >> 5;  // ty 0..7
#pragma unroll
  for (int r = ty; r < 32; r += 8) t[r][tx] = in[(size_t)(k0 + r) * N + n0 + tx];
  __syncthreads();
#pragma unroll
  for (int r = ty; r < 32; r += 8)
    out[(size_t)(n0 + r) * K + k0 + tx] = (bf16_t)t[tx][r];
}

// ------------- row offsets: ro[n] = lower_bound(dst, n) (dst sorted) -------------
__global__ void rowoffk(const int* __restrict__ dst, int* __restrict__ ro, int N, int E) {
  int n = blockIdx.x * blockDim.x + threadIdx.x;
  if (n > N) return;
  if (n == N) { ro[N] = E; return; }
  int lo = 0, hi = E;
  while (lo < hi) { int mid = (lo + hi) >> 1; if (dst[mid] < n) lo = mid + 1; else hi = mid; }
  ro[n] = lo;
}

// ------------- el/er: per node, per head dot(h, al), dot(h, ar) -------------
__global__ void elerk(const bf16_t* __restrict__ Hb, const float* __restrict__ al,
                      const float* __restrict__ ar, float* __restrict__ el,
                      float* __restrict__ er, int N) {
  int node = blockIdx.x * 4 + (threadIdx.x >> 6);
  int lane = threadIdx.x & 63;
  if (node >= N) return;
  bf16x8 v = *(const bf16x8*)(Hb + (size_t)node * 512 + lane * 8);
  int head = lane >> 4;
  int dbase = (lane & 15) * 8;
  float sl = 0.f, sr = 0.f;
#pragma unroll
  for (int t = 0; t < 8; t++) {
    float f = (float)v[t];
    sl += f * al[head * 128 + dbase + t];
    sr += f * ar[head * 128 + dbase + t];
  }
#pragma unroll
  for (int off = 1; off < 16; off <<= 1) {
    sl += __shfl_xor(sl, off);
    sr += __shfl_xor(sr, off);
  }
  if ((lane & 15) == 0) {
    el[node * 4 + head] = sl;
    er[node * 4 + head] = sr;
  }
}

// ------------- edge-softmax aggregation per destination node -------------
// out[n][h*128+d] = elu( sum_e alpha_e,h * H[src_e][h*128+d] + b[h*128+d] )
#define AGG_CHUNK 128
__global__ __launch_bounds__(512) void aggk(
    const bf16_t* __restrict__ Hb, const float* __restrict__ el,
    const float* __restrict__ er, const int* __restrict__ src,
    const int* __restrict__ ro, const float* __restrict__ bias,
    bf16_t* __restrict__ out, int N) {
  int n = blockIdx.x;
  int tid = threadIdx.x;
  int e0 = ro[n], e1 = ro[n + 1];

  __shared__ float s_md[8];              // m[0..3], inv_denom[4..7]
  __shared__ float s_w[AGG_CHUNK * 4];
  __shared__ int s_src[AGG_CHUNK];

  float e_r[4];
  if (tid < 64) {
#pragma unroll
    for (int h = 0; h < 4; h++) e_r[h] = er[n * 4 + h];
    float mx[4] = {-1e30f, -1e30f, -1e30f, -1e30f};
    for (int e = e0 + tid; e < e1; e += 64) {
      int s = src[e];
#pragma unroll
      for (int h = 0; h < 4; h++) {
        float sc = el[s * 4 + h] + e_r[h];
        sc = sc >= 0.f ? sc : 0.2f * sc;
        mx[h] = fmaxf(mx[h], sc);
      }
    }
#pragma unroll
    for (int off = 1; off < 64; off <<= 1)
#pragma unroll
      for (int h = 0; h < 4; h++) mx[h] = fmaxf(mx[h], __shfl_xor(mx[h], off));
    float sm[4] = {0.f, 0.f, 0.f, 0.f};
    for (int e = e0 + tid; e < e1; e += 64) {
      int s = src[e];
#pragma unroll
      for (int h = 0; h < 4; h++) {
        float sc = el[s * 4 + h] + e_r[h];
        sc = sc >= 0.f ? sc : 0.2f * sc;
        sm[h] += __expf(sc - mx[h]);
      }
    }
#pragma unroll
    for (int off = 1; off < 64; off <<= 1)
#pragma unroll
      for (int h = 0; h < 4; h++) sm[h] += __shfl_xor(sm[h], off);
    if (tid == 0) {
#pragma unroll
      for (int h = 0; h < 4; h++) {
        s_md[h] = mx[h];
        s_md[4 + h] = 1.0f / sm[h];
      }
    }
  }
  __syncthreads();

  int h = tid >> 7, d = tid;  // d = full 512-wide index
  float acc = 0.f;
  for (int cs = e0; cs < e1; cs += AGG_CHUNK) {
    int cnt = e1 - cs; if (cnt > AGG_CHUNK) cnt = AGG_CHUNK;
    if (tid < 64) {
      for (int i = tid; i < cnt; i += 64) {
        int s = src[cs + i];
        s_src[i] = s;
#pragma unroll
        for (int h2 = 0; h2 < 4; h2++) {
          float sc = el[s * 4 + h2] + e_r[h2];
          sc = sc >= 0.f ? sc : 0.2f * sc;
          s_w[i * 4 + h2] = __expf(sc - s_md[h2]) * s_md[4 + h2];
        }
      }
    }
    __syncthreads();
    for (int i = 0; i < cnt; i++) {
      float w = s_w[i * 4 + h];
      acc += w * (float)Hb[(size_t)s_src[i] * 512 + d];
    }
    __syncthreads();
  }
  float o = acc + bias[d];
  o = o > 0.f ? o : expm1f(o);
  out[(size_t)n * 512 + d] = (bf16_t)o;
}

// ------------- bf16 MFMA GEMM: C[M][N] = A[M][K] @ Bt[N][K]^T -------------
// EPI=0: store bf16 C.  EPI=1: store fp32 elu(C + bias) (for final FC).
template <int BN, int WM, int WN, int EPI>
__global__ __launch_bounds__(256) void gemm_bt(
    const bf16_t* __restrict__ A, const bf16_t* __restrict__ Bt,
    void* __restrict__ C, const float* __restrict__ bias,
    int M, int N, int K) {
  constexpr int BM = 128, BK = 32;
  constexpr int WTM = BM / WM, WTN = BN / WN;
  constexpr int MF = WTM / 16, NF = WTN / 16;

  __shared__ bf16_t sA[BM][BK];
  __shared__ bf16_t sB[BN][BK];

  const int tid = threadIdx.x;
  const int wid = tid >> 6, lane = tid & 63;
  const int wr = wid / WN, wc = wid % WN;
  const int row0 = blockIdx.x * BM;
  const int col0 = blockIdx.y * BN;

  f32x4 acc[MF][NF];
#pragma unroll
  for (int i = 0; i < MF; i++)
#pragma unroll
    for (int j = 0; j < NF; j++) acc[i][j] = (f32x4){0.f, 0.f, 0.f, 0.f};

  const int lr = lane >> 2;          // row within 16-row staging group
  const int lkb = (lane & 3) * 8;    // k element offset for staging

  for (int k0 = 0; k0 < K; k0 += BK) {
#pragma unroll
    for (int i = 0; i < BM / 16; i += 4) {
      int r = (i + wid) * 16 + lr;
      int grow = row0 + r; if (grow > M - 1) grow = M - 1;
      gload_lds16(A + (size_t)grow * K + k0 + lkb, &sA[(i + wid) * 16][0]);
    }
#pragma unroll
    for (int i = 0; i < BN / 16; i += 4) {
      int r = (i + wid) * 16 + lr;
      gload_lds16(Bt + (size_t)(col0 + r) * K + k0 + lkb, &sB[(i + wid) * 16][0]);
    }
    __syncthreads();
    bf16x8 af[MF], bfr[NF];
#pragma unroll
    for (int i = 0; i < MF; i++)
      af[i] = *(const bf16x8*)&sA[wr * WTM + i * 16 + (lane & 15)][(lane >> 4) * 8];
#pragma unroll
    for (int j = 0; j < NF; j++)
      bfr[j] = *(const bf16x8*)&sB[wc * WTN + j * 16 + (lane & 15)][(lane >> 4) * 8];
#pragma unroll
    for (int i = 0; i < MF; i++)
#pragma unroll
      for (int j = 0; j < NF; j++)
        acc[i][j] = __builtin_amdgcn_mfma_f32_16x16x32_bf16(af[i], bfr[j], acc[i][j], 0, 0, 0);
    __syncthreads();
  }

#pragma unroll
  for (int i = 0; i < MF; i++) {
#pragma unroll
    for (int j = 0; j < NF; j++) {
#pragma unroll
      for (int r = 0; r < 4; r++) {
        int row = row0 + wr * WTM + i * 16 + (lane >> 4) * 4 + r;
        int col = col0 + wc * WTN + j * 16 + (lane & 15);
        if (row < M) {
          float v = acc[i][j][r];
          if constexpr (EPI == 0) {
            ((bf16_t*)C)[(size_t)row * N + col] = (bf16_t)v;
          } else {
            v += bias[col];
            v = v > 0.f ? v : expm1f(v);
            ((float*)C)[(size_t)row * N + col] = v;
          }
        }
      }
    }
  }
}

extern "C" void kernel_launch(void* const* d_in, const int* in_sizes, int n_in,
                              void* d_out, int out_size, void* d_ws, size_t ws_size,
                              hipStream_t stream) {
  const float* feature = (const float*)d_in[0];
  const int* src = (const int*)d_in[1];
  const int* dst = (const int*)d_in[2];
  const float* W1 = (const float*)d_in[3];
  const float* al1 = (const float*)d_in[4];
  const float* ar1 = (const float*)d_in[5];
  const float* b1 = (const float*)d_in[6];
  const float* W2 = (const float*)d_in[7];
  const float* al2 = (const float*)d_in[8];
  const float* ar2 = (const float*)d_in[9];
  const float* b2 = (const float*)d_in[10];
  const float* Wfc = (const float*)d_in[11];
  const float* bfc = (const float*)d_in[12];

  const int N = 20000, E = 320000, INF = 1280, HD = 512;

  char* ws = (char*)d_ws;
  size_t off = 0;
  auto alloc = [&](size_t bytes) {
    void* p = ws + off;
    off += (bytes + 255) & ~(size_t)255;
    return p;
  };
  bf16_t* Xb  = (bf16_t*)alloc((size_t)N * INF * 2);   // 51.2 MB
  bf16_t* W1t = (bf16_t*)alloc((size_t)HD * INF * 2);
  bf16_t* W2t = (bf16_t*)alloc((size_t)HD * HD * 2);
  bf16_t* Wft = (bf16_t*)alloc((size_t)64 * HD * 2);
  bf16_t* Hb  = (bf16_t*)alloc((size_t)N * HD * 2);    // 20.5 MB
  bf16_t* Xn  = (bf16_t*)alloc((size_t)N * HD * 2);    // 20.5 MB
  float* el = (float*)alloc((size_t)N * 4 * 4);
  float* er = (float*)alloc((size_t)N * 4 * 4);
  int* ro = (int*)alloc((size_t)(N + 1) * 4);

  // preprocessing
  castk<<<(N * INF) / (256 * 8), 256, 0, stream>>>(feature, Xb, N * INF);
  {
    dim3 g(HD / 32, INF / 32);
    transk<<<g, 256, 0, stream>>>(W1, W1t, INF, HD);
  }
  {
    dim3 g(HD / 32, HD / 32);
    transk<<<g, 256, 0, stream>>>(W2, W2t, HD, HD);
  }
  {
    dim3 g(64 / 32, HD / 32);
    transk<<<g, 256, 0, stream>>>(Wfc, Wft, HD, 64);
  }
  rowoffk<<<(N + 1 + 255) / 256, 256, 0, stream>>>(dst, ro, N, E);

  dim3 gg((N + 127) / 128, HD / 128);

  // layer 1
  gemm_bt<128, 2, 2, 0><<<gg, 256, 0, stream>>>(Xb, W1t, Hb, nullptr, N, HD, INF);
  elerk<<<N / 4, 256, 0, stream>>>(Hb, al1, ar1, el, er, N);
  aggk<<<N, 512, 0, stream>>>(Hb, el, er, src, ro, b1, Xn, N);

  // layer 2
  gemm_bt<128, 2, 2, 0><<<gg, 256, 0, stream>>>(Xn, W2t, Hb, nullptr, N, HD, HD);
  elerk<<<N / 4, 256, 0, stream>>>(Hb, al2, ar2, el, er, N);
  aggk<<<N, 512, 0, stream>>>(Hb, el, er, src, ro, b2, Xn, N);

  // final FC + elu -> d_out (fp32)
  dim3 gf((N + 127) / 128, 1);
  gemm_bt<64, 4, 1, 1><<<gf, 256, 0, stream>>>(Xn, Wft, d_out, bfc, N, 64, HD);
}

// Round 2
// 263.557 us; speedup vs baseline: 1.4070x; 1.4070x over previous
//
#include <hip/hip_runtime.h>
#include <hip/hip_bf16.h>
#include <math.h>

typedef __bf16 bf16_t;
typedef __bf16 bf16x8 __attribute__((ext_vector_type(8)));
typedef float f32x4 __attribute__((ext_vector_type(4)));

__device__ __forceinline__ void gload_lds16(const void* g, void* l) {
  __builtin_amdgcn_global_load_lds((const __attribute__((address_space(1))) void*)g,
                                   (__attribute__((address_space(3))) void*)l, 16, 0, 0);
}

// ---------------- cast fp32 -> bf16 (vectorized x8) ----------------
__global__ void castk(const float* __restrict__ in, bf16_t* __restrict__ out, int n) {
  int i = (blockIdx.x * blockDim.x + threadIdx.x) * 8;
  if (i >= n) return;
  float4 a = *(const float4*)(in + i);
  float4 b = *(const float4*)(in + i + 4);
  bf16x8 o;
  o[0] = (bf16_t)a.x; o[1] = (bf16_t)a.y; o[2] = (bf16_t)a.z; o[3] = (bf16_t)a.w;
  o[4] = (bf16_t)b.x; o[5] = (bf16_t)b.y; o[6] = (bf16_t)b.z; o[7] = (bf16_t)b.w;
  *(bf16x8*)(out + i) = o;
}

// ------------- transpose + cast: in fp32 [K][N] -> out bf16 [N][K] -------------
__global__ void transk(const float* __restrict__ in, bf16_t* __restrict__ out,
                       int K, int N) {
  __shared__ float t[32][33];
  int n0 = blockIdx.x * 32, k0 = blockIdx.y * 32;
  int tx = threadIdx.x & 31, ty = threadIdx.x >> 5;  // ty 0..7
#pragma unroll
  for (int r = ty; r < 32; r += 8) t[r][tx] = in[(size_t)(k0 + r) * N + n0 + tx];
  __syncthreads();
#pragma unroll
  for (int r = ty; r < 32; r += 8)
    out[(size_t)(n0 + r) * K + k0 + tx] = (bf16_t)t[tx][r];
}

// ------------- row offsets: ro[n] = lower_bound(dst, n) (dst sorted) -------------
__global__ void rowoffk(const int* __restrict__ dst, int* __restrict__ ro, int N, int E) {
  int n = blockIdx.x * blockDim.x + threadIdx.x;
  if (n > N) return;
  if (n == N) { ro[N] = E; return; }
  int lo = 0, hi = E;
  while (lo < hi) { int mid = (lo + hi) >> 1; if (dst[mid] < n) lo = mid + 1; else hi = mid; }
  ro[n] = lo;
}

// ------------- el/er: per node, per head dot(h, al), dot(h, ar) -------------
__global__ void elerk(const bf16_t* __restrict__ Hb, const float* __restrict__ al,
                      const float* __restrict__ ar, float* __restrict__ el,
                      float* __restrict__ er, int N) {
  int node = blockIdx.x * 4 + (threadIdx.x >> 6);
  int lane = threadIdx.x & 63;
  if (node >= N) return;
  bf16x8 v = *(const bf16x8*)(Hb + (size_t)node * 512 + lane * 8);
  int head = lane >> 4;
  int dbase = (lane & 15) * 8;
  float sl = 0.f, sr = 0.f;
#pragma unroll
  for (int t = 0; t < 8; t++) {
    float f = (float)v[t];
    sl += f * al[head * 128 + dbase + t];
    sr += f * ar[head * 128 + dbase + t];
  }
#pragma unroll
  for (int off = 1; off < 16; off <<= 1) {
    sl += __shfl_xor(sl, off);
    sr += __shfl_xor(sr, off);
  }
  if ((lane & 15) == 0) {
    el[node * 4 + head] = sl;
    er[node * 4 + head] = sr;
  }
}

// ------------- edge-softmax aggregation: ONE WAVE PER NODE -------------
// out[n][d] = elu( sum_e alpha_{e,h(d)} * H[src_e][d] + bias[d] ),  d = lane*8..+8
#define AGG_WAVES 4
__global__ __launch_bounds__(256) void aggk(
    const bf16_t* __restrict__ Hb, const float* __restrict__ el,
    const float* __restrict__ er, const int* __restrict__ src,
    const int* __restrict__ ro, const float* __restrict__ bias,
    bf16_t* __restrict__ out, int N) {
  __shared__ float s_p[AGG_WAVES][64][4];
  __shared__ int s_src[AGG_WAVES][64];
  const int w = threadIdx.x >> 6, lane = threadIdx.x & 63;
  const int n = blockIdx.x * AGG_WAVES + w;
  if (n >= N) return;
  const int e0 = ro[n], e1 = ro[n + 1];
  const float4 erv = *(const float4*)(er + (size_t)n * 4);
  const int h = lane >> 4;

  // ---- pass 1: online softmax max + denom across all edges ----
  float m0 = -1e30f, m1 = -1e30f, m2 = -1e30f, m3 = -1e30f;
  float d0 = 0.f, d1 = 0.f, d2 = 0.f, d3 = 0.f;
  for (int base = e0; base < e1; base += 64) {
    int e = base + lane;
    float c0 = -1e30f, c1 = -1e30f, c2 = -1e30f, c3 = -1e30f;
    if (e < e1) {
      int s = src[e];
      float4 ev = *(const float4*)(el + (size_t)s * 4);
      c0 = ev.x + erv.x; c0 = c0 >= 0.f ? c0 : 0.2f * c0;
      c1 = ev.y + erv.y; c1 = c1 >= 0.f ? c1 : 0.2f * c1;
      c2 = ev.z + erv.z; c2 = c2 >= 0.f ? c2 : 0.2f * c2;
      c3 = ev.w + erv.w; c3 = c3 >= 0.f ? c3 : 0.2f * c3;
    }
    float r0 = c0, r1 = c1, r2 = c2, r3 = c3;
#pragma unroll
    for (int off = 1; off < 64; off <<= 1) {
      r0 = fmaxf(r0, __shfl_xor(r0, off));
      r1 = fmaxf(r1, __shfl_xor(r1, off));
      r2 = fmaxf(r2, __shfl_xor(r2, off));
      r3 = fmaxf(r3, __shfl_xor(r3, off));
    }
    float n0 = fmaxf(m0, r0), n1 = fmaxf(m1, r1), n2 = fmaxf(m2, r2), n3 = fmaxf(m3, r3);
    float t0 = (base + lane < e1) ? __expf(c0 - n0) : 0.f;
    float t1 = (base + lane < e1) ? __expf(c1 - n1) : 0.f;
    float t2 = (base + lane < e1) ? __expf(c2 - n2) : 0.f;
    float t3 = (base + lane < e1) ? __expf(c3 - n3) : 0.f;
#pragma unroll
    for (int off = 1; off < 64; off <<= 1) {
      t0 += __shfl_xor(t0, off);
      t1 += __shfl_xor(t1, off);
      t2 += __shfl_xor(t2, off);
      t3 += __shfl_xor(t3, off);
    }
    d0 = d0 * __expf(m0 - n0) + t0;
    d1 = d1 * __expf(m1 - n1) + t1;
    d2 = d2 * __expf(m2 - n2) + t2;
    d3 = d3 * __expf(m3 - n3) + t3;
    m0 = n0; m1 = n1; m2 = n2; m3 = n3;
  }
  const float i0 = 1.0f / d0, i1 = 1.0f / d1, i2 = 1.0f / d2, i3 = 1.0f / d3;

  // ---- pass 2: weighted aggregation, bf16x8 per lane ----
  float acc[8] = {0.f, 0.f, 0.f, 0.f, 0.f, 0.f, 0.f, 0.f};
  for (int base = e0; base < e1; base += 64) {
    int e = base + lane;
    if (e < e1) {
      int s = src[e];
      s_src[w][lane] = s;
      float4 ev = *(const float4*)(el + (size_t)s * 4);
      float c0 = ev.x + erv.x; c0 = c0 >= 0.f ? c0 : 0.2f * c0;
      float c1 = ev.y + erv.y; c1 = c1 >= 0.f ? c1 : 0.2f * c1;
      float c2 = ev.z + erv.z; c2 = c2 >= 0.f ? c2 : 0.2f * c2;
      float c3 = ev.w + erv.w; c3 = c3 >= 0.f ? c3 : 0.2f * c3;
      float4 p;
      p.x = __expf(c0 - m0) * i0;
      p.y = __expf(c1 - m1) * i1;
      p.z = __expf(c2 - m2) * i2;
      p.w = __expf(c3 - m3) * i3;
      *(float4*)&s_p[w][lane][0] = p;
    }
    __threadfence_block();  // lgkmcnt drain: own-wave LDS writes visible to reads
    int cnt = e1 - base; if (cnt > 64) cnt = 64;
    for (int i = 0; i < cnt; i++) {
      int si = s_src[w][i];
      float wt = s_p[w][i][h];
      bf16x8 v = *(const bf16x8*)(Hb + (size_t)si * 512 + lane * 8);
#pragma unroll
      for (int t = 0; t < 8; t++) acc[t] += wt * (float)v[t];
    }
  }

  // ---- epilogue: bias + elu, store bf16x8 ----
  bf16x8 o;
#pragma unroll
  for (int t = 0; t < 8; t++) {
    float v = acc[t] + bias[lane * 8 + t];
    v = v > 0.f ? v : expm1f(v);
    o[t] = (bf16_t)v;
  }
  *(bf16x8*)(out + (size_t)n * 512 + lane * 8) = o;
}

// ------------- bf16 MFMA GEMM: C[M][N] = A[M][K] @ Bt[N][K]^T -------------
// EPI=0: store bf16 C.  EPI=1: store fp32 elu(C + bias) (for final FC).
template <int BN, int WM, int WN, int EPI>
__global__ __launch_bounds__(256) void gemm_bt(
    const bf16_t* __restrict__ A, const bf16_t* __restrict__ Bt,
    void* __restrict__ C, const float* __restrict__ bias,
    int M, int N, int K) {
  constexpr int BM = 128, BK = 32;
  constexpr int WTM = BM / WM, WTN = BN / WN;
  constexpr int MF = WTM / 16, NF = WTN / 16;

  __shared__ bf16_t sA[BM][BK];
  __shared__ bf16_t sB[BN][BK];

  const int tid = threadIdx.x;
  const int wid = tid >> 6, lane = tid & 63;
  const int wr = wid / WN, wc = wid % WN;
  const int row0 = blockIdx.x * BM;
  const int col0 = blockIdx.y * BN;

  f32x4 acc[MF][NF];
#pragma unroll
  for (int i = 0; i < MF; i++)
#pragma unroll
    for (int j = 0; j < NF; j++) acc[i][j] = (f32x4){0.f, 0.f, 0.f, 0.f};

  const int lr = lane >> 2;          // row within 16-row staging group
  const int lkb = (lane & 3) * 8;    // k element offset for staging

  for (int k0 = 0; k0 < K; k0 += BK) {
#pragma unroll
    for (int i = 0; i < BM / 16; i += 4) {
      int r = (i + wid) * 16 + lr;
      int grow = row0 + r; if (grow > M - 1) grow = M - 1;
      gload_lds16(A + (size_t)grow * K + k0 + lkb, &sA[(i + wid) * 16][0]);
    }
#pragma unroll
    for (int i = 0; i < BN / 16; i += 4) {
      int r = (i + wid) * 16 + lr;
      gload_lds16(Bt + (size_t)(col0 + r) * K + k0 + lkb, &sB[(i + wid) * 16][0]);
    }
    __syncthreads();
    bf16x8 af[MF], bfr[NF];
#pragma unroll
    for (int i = 0; i < MF; i++)
      af[i] = *(const bf16x8*)&sA[wr * WTM + i * 16 + (lane & 15)][(lane >> 4) * 8];
#pragma unroll
    for (int j = 0; j < NF; j++)
      bfr[j] = *(const bf16x8*)&sB[wc * WTN + j * 16 + (lane & 15)][(lane >> 4) * 8];
#pragma unroll
    for (int i = 0; i < MF; i++)
#pragma unroll
      for (int j = 0; j < NF; j++)
        acc[i][j] = __builtin_amdgcn_mfma_f32_16x16x32_bf16(af[i], bfr[j], acc[i][j], 0, 0, 0);
    __syncthreads();
  }

#pragma unroll
  for (int i = 0; i < MF; i++) {
#pragma unroll
    for (int j = 0; j < NF; j++) {
#pragma unroll
      for (int r = 0; r < 4; r++) {
        int row = row0 + wr * WTM + i * 16 + (lane >> 4) * 4 + r;
        int col = col0 + wc * WTN + j * 16 + (lane & 15);
        if (row < M) {
          float v = acc[i][j][r];
          if constexpr (EPI == 0) {
            ((bf16_t*)C)[(size_t)row * N + col] = (bf16_t)v;
          } else {
            v += bias[col];
            v = v > 0.f ? v : expm1f(v);
            ((float*)C)[(size_t)row * N + col] = v;
          }
        }
      }
    }
  }
}

extern "C" void kernel_launch(void* const* d_in, const int* in_sizes, int n_in,
                              void* d_out, int out_size, void* d_ws, size_t ws_size,
                              hipStream_t stream) {
  const float* feature = (const float*)d_in[0];
  const int* src = (const int*)d_in[1];
  const int* dst = (const int*)d_in[2];
  const float* W1 = (const float*)d_in[3];
  const float* al1 = (const float*)d_in[4];
  const float* ar1 = (const float*)d_in[5];
  const float* b1 = (const float*)d_in[6];
  const float* W2 = (const float*)d_in[7];
  const float* al2 = (const float*)d_in[8];
  const float* ar2 = (const float*)d_in[9];
  const float* b2 = (const float*)d_in[10];
  const float* Wfc = (const float*)d_in[11];
  const float* bfc = (const float*)d_in[12];

  const int N = 20000, E = 320000, INF = 1280, HD = 512;

  char* ws = (char*)d_ws;
  size_t off = 0;
  auto alloc = [&](size_t bytes) {
    void* p = ws + off;
    off += (bytes + 255) & ~(size_t)255;
    return p;
  };
  bf16_t* Xb  = (bf16_t*)alloc((size_t)N * INF * 2);   // 51.2 MB
  bf16_t* W1t = (bf16_t*)alloc((size_t)HD * INF * 2);
  bf16_t* W2t = (bf16_t*)alloc((size_t)HD * HD * 2);
  bf16_t* Wft = (bf16_t*)alloc((size_t)64 * HD * 2);
  bf16_t* Hb  = (bf16_t*)alloc((size_t)N * HD * 2);    // 20.5 MB
  bf16_t* Xn  = (bf16_t*)alloc((size_t)N * HD * 2);    // 20.5 MB
  float* el = (float*)alloc((size_t)N * 4 * 4);
  float* er = (float*)alloc((size_t)N * 4 * 4);
  int* ro = (int*)alloc((size_t)(N + 1) * 4);

  // preprocessing
  castk<<<(N * INF) / (256 * 8), 256, 0, stream>>>(feature, Xb, N * INF);
  {
    dim3 g(HD / 32, INF / 32);
    transk<<<g, 256, 0, stream>>>(W1, W1t, INF, HD);
  }
  {
    dim3 g(HD / 32, HD / 32);
    transk<<<g, 256, 0, stream>>>(W2, W2t, HD, HD);
  }
  {
    dim3 g(64 / 32, HD / 32);
    transk<<<g, 256, 0, stream>>>(Wfc, Wft, HD, 64);
  }
  rowoffk<<<(N + 1 + 255) / 256, 256, 0, stream>>>(dst, ro, N, E);

  dim3 gg((N + 127) / 128, HD / 128);
  const int aggBlocks = (N + AGG_WAVES - 1) / AGG_WAVES;

  // layer 1
  gemm_bt<128, 2, 2, 0><<<gg, 256, 0, stream>>>(Xb, W1t, Hb, nullptr, N, HD, INF);
  elerk<<<N / 4, 256, 0, stream>>>(Hb, al1, ar1, el, er, N);
  aggk<<<aggBlocks, 256, 0, stream>>>(Hb, el, er, src, ro, b1, Xn, N);

  // layer 2
  gemm_bt<128, 2, 2, 0><<<gg, 256, 0, stream>>>(Xn, W2t, Hb, nullptr, N, HD, HD);
  elerk<<<N / 4, 256, 0, stream>>>(Hb, al2, ar2, el, er, N);
  aggk<<<aggBlocks, 256, 0, stream>>>(Hb, el, er, src, ro, b2, Xn, N);

  // final FC + elu -> d_out (fp32)
  dim3 gf((N + 127) / 128, 1);
  gemm_bt<64, 4, 1, 1><<<gf, 256, 0, stream>>>(Xn, Wft, d_out, bfc, N, 64, HD);
}

// Round 3
// 260.133 us; speedup vs baseline: 1.4255x; 1.0132x over previous
//
#include <hip/hip_runtime.h>
#include <hip/hip_bf16.h>
#include <math.h>

typedef __bf16 bf16_t;
typedef __bf16 bf16x8 __attribute__((ext_vector_type(8)));
typedef float f32x4 __attribute__((ext_vector_type(4)));

__device__ __forceinline__ void gload_lds16(const void* g, void* l) {
  __builtin_amdgcn_global_load_lds((const __attribute__((address_space(1))) void*)g,
                                   (__attribute__((address_space(3))) void*)l, 16, 0, 0);
}

// ---------------- cast fp32 -> bf16 (vectorized x8) ----------------
__global__ void castk(const float* __restrict__ in, bf16_t* __restrict__ out, int n) {
  int i = (blockIdx.x * blockDim.x + threadIdx.x) * 8;
  if (i >= n) return;
  float4 a = *(const float4*)(in + i);
  float4 b = *(const float4*)(in + i + 4);
  bf16x8 o;
  o[0] = (bf16_t)a.x; o[1] = (bf16_t)a.y; o[2] = (bf16_t)a.z; o[3] = (bf16_t)a.w;
  o[4] = (bf16_t)b.x; o[5] = (bf16_t)b.y; o[6] = (bf16_t)b.z; o[7] = (bf16_t)b.w;
  *(bf16x8*)(out + i) = o;
}

// ------------- transpose + cast: in fp32 [K][N] -> out bf16 [N][K] -------------
__global__ void transk(const float* __restrict__ in, bf16_t* __restrict__ out,
                       int K, int N) {
  __shared__ float t[32][33];
  int n0 = blockIdx.x * 32, k0 = blockIdx.y * 32;
  int tx = threadIdx.x & 31, ty = threadIdx.x >> 5;  // ty 0..7
#pragma unroll
  for (int r = ty; r < 32; r += 8) t[r][tx] = in[(size_t)(k0 + r) * N + n0 + tx];
  __syncthreads();
#pragma unroll
  for (int r = ty; r < 32; r += 8)
    out[(size_t)(n0 + r) * K + k0 + tx] = (bf16_t)t[tx][r];
}

// ------------- row offsets: ro[n] = lower_bound(dst, n) (dst sorted) -------------
__global__ void rowoffk(const int* __restrict__ dst, int* __restrict__ ro, int N, int E) {
  int n = blockIdx.x * blockDim.x + threadIdx.x;
  if (n > N) return;
  if (n == N) { ro[N] = E; return; }
  int lo = 0, hi = E;
  while (lo < hi) { int mid = (lo + hi) >> 1; if (dst[mid] < n) lo = mid + 1; else hi = mid; }
  ro[n] = lo;
}

// ------------- el/er: per node, per head dot(h, al), dot(h, ar) -------------
__global__ void elerk(const bf16_t* __restrict__ Hb, const float* __restrict__ al,
                      const float* __restrict__ ar, float* __restrict__ el,
                      float* __restrict__ er, int N) {
  int node = blockIdx.x * 4 + (threadIdx.x >> 6);
  int lane = threadIdx.x & 63;
  if (node >= N) return;
  bf16x8 v = *(const bf16x8*)(Hb + (size_t)node * 512 + lane * 8);
  int head = lane >> 4;
  int dbase = (lane & 15) * 8;
  float sl = 0.f, sr = 0.f;
#pragma unroll
  for (int t = 0; t < 8; t++) {
    float f = (float)v[t];
    sl += f * al[head * 128 + dbase + t];
    sr += f * ar[head * 128 + dbase + t];
  }
#pragma unroll
  for (int off = 1; off < 16; off <<= 1) {
    sl += __shfl_xor(sl, off);
    sr += __shfl_xor(sr, off);
  }
  if ((lane & 15) == 0) {
    el[node * 4 + head] = sl;
    er[node * 4 + head] = sr;
  }
}

// ------------- edge-softmax aggregation: ONE WAVE PER NODE, single online pass --
// out[n][d] = elu( (1/denom_h) * sum_e exp(score_e,h - m_h) * H[src_e][d] + bias[d] )
#define AGG_WAVES 4
__global__ __launch_bounds__(256) void aggk(
    const bf16_t* __restrict__ Hb, const float* __restrict__ el,
    const float* __restrict__ er, const int* __restrict__ src,
    const int* __restrict__ ro, const float* __restrict__ bias,
    bf16_t* __restrict__ out, int N) {
  __shared__ float s_p[AGG_WAVES][64][4];
  __shared__ int s_src[AGG_WAVES][64];
  const int w = threadIdx.x >> 6, lane = threadIdx.x & 63;
  const int n = blockIdx.x * AGG_WAVES + w;
  if (n >= N) return;
  const int e0 = ro[n], e1 = ro[n + 1];
  const float4 erv = *(const float4*)(er + (size_t)n * 4);
  const int h = lane >> 4;

  float m0 = -1e30f, m1 = -1e30f, m2 = -1e30f, m3 = -1e30f;
  float d0 = 0.f, d1 = 0.f, d2 = 0.f, d3 = 0.f;
  float acc[8] = {0.f, 0.f, 0.f, 0.f, 0.f, 0.f, 0.f, 0.f};

  for (int base = e0; base < e1; base += 64) {
    const int e = base + lane;
    const bool valid = e < e1;
    const int s = valid ? src[e] : 0;
    float4 ev = *(const float4*)(el + (size_t)s * 4);
    float c0 = ev.x + erv.x; c0 = c0 >= 0.f ? c0 : 0.2f * c0;
    float c1 = ev.y + erv.y; c1 = c1 >= 0.f ? c1 : 0.2f * c1;
    float c2 = ev.z + erv.z; c2 = c2 >= 0.f ? c2 : 0.2f * c2;
    float c3 = ev.w + erv.w; c3 = c3 >= 0.f ? c3 : 0.2f * c3;
    if (!valid) { c0 = c1 = c2 = c3 = -1e30f; }

    // wave-max per head
    float r0 = c0, r1 = c1, r2 = c2, r3 = c3;
#pragma unroll
    for (int off = 1; off < 64; off <<= 1) {
      r0 = fmaxf(r0, __shfl_xor(r0, off));
      r1 = fmaxf(r1, __shfl_xor(r1, off));
      r2 = fmaxf(r2, __shfl_xor(r2, off));
      r3 = fmaxf(r3, __shfl_xor(r3, off));
    }
    const float n0 = fmaxf(m0, r0), n1 = fmaxf(m1, r1);
    const float n2 = fmaxf(m2, r2), n3 = fmaxf(m3, r3);
    // rescale running acc + denom (first chunk: exp(-1e30-x)=0 and acc=0)
    const float s0 = __expf(m0 - n0), s1 = __expf(m1 - n1);
    const float s2 = __expf(m2 - n2), s3 = __expf(m3 - n3);
    const float sh = h == 0 ? s0 : h == 1 ? s1 : h == 2 ? s2 : s3;
#pragma unroll
    for (int t = 0; t < 8; t++) acc[t] *= sh;

    // unnormalized weights (pad lanes: exp(-1e30-n)=0 exactly)
    const float p0 = __expf(c0 - n0), p1 = __expf(c1 - n1);
    const float p2 = __expf(c2 - n2), p3 = __expf(c3 - n3);
    float t0 = p0, t1 = p1, t2 = p2, t3 = p3;
#pragma unroll
    for (int off = 1; off < 64; off <<= 1) {
      t0 += __shfl_xor(t0, off);
      t1 += __shfl_xor(t1, off);
      t2 += __shfl_xor(t2, off);
      t3 += __shfl_xor(t3, off);
    }
    d0 = d0 * s0 + t0; d1 = d1 * s1 + t1; d2 = d2 * s2 + t2; d3 = d3 * s3 + t3;
    m0 = n0; m1 = n1; m2 = n2; m3 = n3;

    s_src[w][lane] = s;
    float4 pv; pv.x = p0; pv.y = p1; pv.z = p2; pv.w = p3;
    *(float4*)&s_p[w][lane][0] = pv;
    __threadfence_block();  // drain ds writes before same-wave reads

    // ---- grouped aggregation: 8 gathers in flight per wave ----
    const int cnt = (e1 - base) < 64 ? (e1 - base) : 64;
    const int cnt8 = (cnt + 7) & ~7;  // pad entries have p=0, src=0 (L1-hot)
    for (int i = 0; i < cnt8; i += 8) {
      int ss[8]; float ww[8];
#pragma unroll
      for (int j = 0; j < 8; j++) {
        ss[j] = s_src[w][i + j];
        ww[j] = s_p[w][i + j][h];
      }
      bf16x8 v[8];
#pragma unroll
      for (int j = 0; j < 8; j++)
        v[j] = *(const bf16x8*)(Hb + (size_t)ss[j] * 512 + lane * 8);
#pragma unroll
      for (int j = 0; j < 8; j++)
#pragma unroll
        for (int t = 0; t < 8; t++) acc[t] += ww[j] * (float)v[j][t];
    }
  }

  const float i0 = d0 > 0.f ? 1.0f / d0 : 0.f;
  const float i1 = d1 > 0.f ? 1.0f / d1 : 0.f;
  const float i2 = d2 > 0.f ? 1.0f / d2 : 0.f;
  const float i3 = d3 > 0.f ? 1.0f / d3 : 0.f;
  const float ih = h == 0 ? i0 : h == 1 ? i1 : h == 2 ? i2 : i3;
  bf16x8 o;
#pragma unroll
  for (int t = 0; t < 8; t++) {
    float v = acc[t] * ih + bias[lane * 8 + t];
    v = v > 0.f ? v : expm1f(v);
    o[t] = (bf16_t)v;
  }
  *(bf16x8*)(out + (size_t)n * 512 + lane * 8) = o;
}

// ------------- bf16 MFMA GEMM: C[M][N] = A[M][K] @ Bt[N][K]^T -------------
// 1D grid + XCD-chunked bijective swizzle (col-fastest in chunk -> A-panel L2 reuse)
// EPI=0: store bf16 C.  EPI=1: store fp32 elu(C + bias) (for final FC).
template <int BN, int WM, int WN, int EPI>
__global__ __launch_bounds__(256) void gemm_bt(
    const bf16_t* __restrict__ A, const bf16_t* __restrict__ Bt,
    void* __restrict__ C, const float* __restrict__ bias,
    int M, int N, int K) {
  constexpr int BM = 128, BK = 32;
  constexpr int WTM = BM / WM, WTN = BN / WN;
  constexpr int MF = WTM / 16, NF = WTN / 16;

  __shared__ bf16_t sA[BM][BK];
  __shared__ bf16_t sB[BN][BK];

  const int tid = threadIdx.x;
  const int wid = tid >> 6, lane = tid & 63;
  const int wr = wid / WN, wc = wid % WN;

  // XCD-chunked bijective swizzle (m204)
  const int nby = N / BN;
  const int nwg = gridDim.x;
  const int q = nwg >> 3, r = nwg & 7;
  const int xcd = blockIdx.x & 7, pos = blockIdx.x >> 3;
  const int wg = (xcd < r ? xcd * (q + 1) : r * (q + 1) + (xcd - r) * q) + pos;
  const int row0 = (wg / nby) * BM;
  const int col0 = (wg % nby) * BN;

  f32x4 acc[MF][NF];
#pragma unroll
  for (int i = 0; i < MF; i++)
#pragma unroll
    for (int j = 0; j < NF; j++) acc[i][j] = (f32x4){0.f, 0.f, 0.f, 0.f};

  const int lr = lane >> 2;          // row within 16-row staging group
  const int lkb = (lane & 3) * 8;    // k element offset for staging

  for (int k0 = 0; k0 < K; k0 += BK) {
#pragma unroll
    for (int i = 0; i < BM / 16; i += 4) {
      int r2 = (i + wid) * 16 + lr;
      int grow = row0 + r2; if (grow > M - 1) grow = M - 1;
      gload_lds16(A + (size_t)grow * K + k0 + lkb, &sA[(i + wid) * 16][0]);
    }
#pragma unroll
    for (int i = 0; i < BN / 16; i += 4) {
      int r2 = (i + wid) * 16 + lr;
      gload_lds16(Bt + (size_t)(col0 + r2) * K + k0 + lkb, &sB[(i + wid) * 16][0]);
    }
    __syncthreads();
    bf16x8 af[MF], bfr[NF];
#pragma unroll
    for (int i = 0; i < MF; i++)
      af[i] = *(const bf16x8*)&sA[wr * WTM + i * 16 + (lane & 15)][(lane >> 4) * 8];
#pragma unroll
    for (int j = 0; j < NF; j++)
      bfr[j] = *(const bf16x8*)&sB[wc * WTN + j * 16 + (lane & 15)][(lane >> 4) * 8];
#pragma unroll
    for (int i = 0; i < MF; i++)
#pragma unroll
      for (int j = 0; j < NF; j++)
        acc[i][j] = __builtin_amdgcn_mfma_f32_16x16x32_bf16(af[i], bfr[j], acc[i][j], 0, 0, 0);
    __syncthreads();
  }

#pragma unroll
  for (int i = 0; i < MF; i++) {
#pragma unroll
    for (int j = 0; j < NF; j++) {
#pragma unroll
      for (int rr = 0; rr < 4; rr++) {
        int row = row0 + wr * WTM + i * 16 + (lane >> 4) * 4 + rr;
        int col = col0 + wc * WTN + j * 16 + (lane & 15);
        if (row < M) {
          float v = acc[i][j][rr];
          if constexpr (EPI == 0) {
            ((bf16_t*)C)[(size_t)row * N + col] = (bf16_t)v;
          } else {
            v += bias[col];
            v = v > 0.f ? v : expm1f(v);
            ((float*)C)[(size_t)row * N + col] = v;
          }
        }
      }
    }
  }
}

extern "C" void kernel_launch(void* const* d_in, const int* in_sizes, int n_in,
                              void* d_out, int out_size, void* d_ws, size_t ws_size,
                              hipStream_t stream) {
  const float* feature = (const float*)d_in[0];
  const int* src = (const int*)d_in[1];
  const int* dst = (const int*)d_in[2];
  const float* W1 = (const float*)d_in[3];
  const float* al1 = (const float*)d_in[4];
  const float* ar1 = (const float*)d_in[5];
  const float* b1 = (const float*)d_in[6];
  const float* W2 = (const float*)d_in[7];
  const float* al2 = (const float*)d_in[8];
  const float* ar2 = (const float*)d_in[9];
  const float* b2 = (const float*)d_in[10];
  const float* Wfc = (const float*)d_in[11];
  const float* bfc = (const float*)d_in[12];

  const int N = 20000, E = 320000, INF = 1280, HD = 512;

  char* ws = (char*)d_ws;
  size_t off = 0;
  auto alloc = [&](size_t bytes) {
    void* p = ws + off;
    off += (bytes + 255) & ~(size_t)255;
    return p;
  };
  bf16_t* Xb  = (bf16_t*)alloc((size_t)N * INF * 2);   // 51.2 MB
  bf16_t* W1t = (bf16_t*)alloc((size_t)HD * INF * 2);
  bf16_t* W2t = (bf16_t*)alloc((size_t)HD * HD * 2);
  bf16_t* Wft = (bf16_t*)alloc((size_t)64 * HD * 2);
  bf16_t* Hb  = (bf16_t*)alloc((size_t)N * HD * 2);    // 20.5 MB
  bf16_t* Xn  = (bf16_t*)alloc((size_t)N * HD * 2);    // 20.5 MB
  float* el = (float*)alloc((size_t)N * 4 * 4);
  float* er = (float*)alloc((size_t)N * 4 * 4);
  int* ro = (int*)alloc((size_t)(N + 1) * 4);

  // preprocessing
  castk<<<(N * INF) / (256 * 8), 256, 0, stream>>>(feature, Xb, N * INF);
  {
    dim3 g(HD / 32, INF / 32);
    transk<<<g, 256, 0, stream>>>(W1, W1t, INF, HD);
  }
  {
    dim3 g(HD / 32, HD / 32);
    transk<<<g, 256, 0, stream>>>(W2, W2t, HD, HD);
  }
  {
    dim3 g(64 / 32, HD / 32);
    transk<<<g, 256, 0, stream>>>(Wfc, Wft, HD, 64);
  }
  rowoffk<<<(N + 1 + 255) / 256, 256, 0, stream>>>(dst, ro, N, E);

  const int nbx = (N + 127) / 128;
  const int aggBlocks = (N + AGG_WAVES - 1) / AGG_WAVES;

  // layer 1
  gemm_bt<128, 2, 2, 0><<<nbx * (HD / 128), 256, 0, stream>>>(Xb, W1t, Hb, nullptr, N, HD, INF);
  elerk<<<N / 4, 256, 0, stream>>>(Hb, al1, ar1, el, er, N);
  aggk<<<aggBlocks, 256, 0, stream>>>(Hb, el, er, src, ro, b1, Xn, N);

  // layer 2
  gemm_bt<128, 2, 2, 0><<<nbx * (HD / 128), 256, 0, stream>>>(Xn, W2t, Hb, nullptr, N, HD, HD);
  elerk<<<N / 4, 256, 0, stream>>>(Hb, al2, ar2, el, er, N);
  aggk<<<aggBlocks, 256, 0, stream>>>(Hb, el, er, src, ro, b2, Xn, N);

  // final FC + elu -> d_out (fp32)
  gemm_bt<64, 4, 1, 1><<<nbx, 256, 0, stream>>>(Xn, Wft, d_out, bfc, N, 64, HD);
}

// Round 4
// 242.610 us; speedup vs baseline: 1.5285x; 1.0722x over previous
//
#include <hip/hip_runtime.h>
#include <hip/hip_bf16.h>
#include <math.h>

typedef __bf16 bf16_t;
typedef __bf16 bf16x8 __attribute__((ext_vector_type(8)));
typedef float f32x4 __attribute__((ext_vector_type(4)));

__device__ __forceinline__ void gload_lds16(const void* g, void* l) {
  __builtin_amdgcn_global_load_lds((const __attribute__((address_space(1))) void*)g,
                                   (__attribute__((address_space(3))) void*)l, 16, 0, 0);
}

// ---------------- cast fp32 -> bf16 (vectorized x8) ----------------
__global__ void castk(const float* __restrict__ in, bf16_t* __restrict__ out, int n) {
  int i = (blockIdx.x * blockDim.x + threadIdx.x) * 8;
  if (i >= n) return;
  float4 a = *(const float4*)(in + i);
  float4 b = *(const float4*)(in + i + 4);
  bf16x8 o;
  o[0] = (bf16_t)a.x; o[1] = (bf16_t)a.y; o[2] = (bf16_t)a.z; o[3] = (bf16_t)a.w;
  o[4] = (bf16_t)b.x; o[5] = (bf16_t)b.y; o[6] = (bf16_t)b.z; o[7] = (bf16_t)b.w;
  *(bf16x8*)(out + i) = o;
}

// ------------- transpose + cast: in fp32 [K][N] -> out bf16 [N][K] -------------
__global__ void transk(const float* __restrict__ in, bf16_t* __restrict__ out,
                       int K, int N) {
  __shared__ float t[32][33];
  int n0 = blockIdx.x * 32, k0 = blockIdx.y * 32;
  int tx = threadIdx.x & 31, ty = threadIdx.x >> 5;  // ty 0..7
#pragma unroll
  for (int r = ty; r < 32; r += 8) t[r][tx] = in[(size_t)(k0 + r) * N + n0 + tx];
  __syncthreads();
#pragma unroll
  for (int r = ty; r < 32; r += 8)
    out[(size_t)(n0 + r) * K + k0 + tx] = (bf16_t)t[tx][r];
}

// ------------- row offsets: ro[n] = lower_bound(dst, n) (dst sorted) -------------
__global__ void rowoffk(const int* __restrict__ dst, int* __restrict__ ro, int N, int E) {
  int n = blockIdx.x * blockDim.x + threadIdx.x;
  if (n > N) return;
  if (n == N) { ro[N] = E; return; }
  int lo = 0, hi = E;
  while (lo < hi) { int mid = (lo + hi) >> 1; if (dst[mid] < n) lo = mid + 1; else hi = mid; }
  ro[n] = lo;
}

// ------------- el/er: per node, per head dot(h, al), dot(h, ar) -------------
__global__ void elerk(const bf16_t* __restrict__ Hb, const float* __restrict__ al,
                      const float* __restrict__ ar, float* __restrict__ el,
                      float* __restrict__ er, int N) {
  int node = blockIdx.x * 4 + (threadIdx.x >> 6);
  int lane = threadIdx.x & 63;
  if (node >= N) return;
  bf16x8 v = *(const bf16x8*)(Hb + (size_t)node * 512 + lane * 8);
  int head = lane >> 4;
  int dbase = (lane & 15) * 8;
  float sl = 0.f, sr = 0.f;
#pragma unroll
  for (int t = 0; t < 8; t++) {
    float f = (float)v[t];
    sl += f * al[head * 128 + dbase + t];
    sr += f * ar[head * 128 + dbase + t];
  }
#pragma unroll
  for (int off = 1; off < 16; off <<= 1) {
    sl += __shfl_xor(sl, off);
    sr += __shfl_xor(sr, off);
  }
  if ((lane & 15) == 0) {
    el[node * 4 + head] = sl;
    er[node * 4 + head] = sr;
  }
}

// ------------- edge-softmax aggregation: ONE WAVE PER NODE -------------
// Softmax phase layout: lane = h*16 + j  (head h, edge slot j, 16-edge chunks).
// Agg phase layout:     lane covers dims [lane*8, lane*8+8) -> same h = lane>>4,
// so per-head online-softmax state (m, d, rescale) is group-coherent in both.
#define AGG_WAVES 4
__global__ __launch_bounds__(256, 6) void aggk(
    const bf16_t* __restrict__ Hb, const float* __restrict__ el,
    const float* __restrict__ er, const int* __restrict__ src,
    const int* __restrict__ ro, const float* __restrict__ bias,
    bf16_t* __restrict__ out, int N) {
  __shared__ float s_p[AGG_WAVES][64];
  __shared__ int s_src[AGG_WAVES][16];
  const int w = threadIdx.x >> 6, lane = threadIdx.x & 63;
  const int n = blockIdx.x * AGG_WAVES + w;
  if (n >= N) return;
  const int e0 = ro[n], e1 = ro[n + 1];
  const int h = lane >> 4;   // head (both phases)
  const int j = lane & 15;   // edge slot (softmax phase)
  const float erh = er[(size_t)n * 4 + h];

  float m = -1e30f, d = 0.f;
  float acc[8] = {0.f, 0.f, 0.f, 0.f, 0.f, 0.f, 0.f, 0.f};

  for (int base = e0; base < e1; base += 16) {
    const int e = base + j;
    const bool valid = e < e1;
    const int s = valid ? src[e] : 0;
    // one (edge, head) score per lane
    float c = el[(size_t)s * 4 + h] + erh;
    c = c >= 0.f ? c : 0.2f * c;
    if (!valid) c = -1e30f;
    // 16-lane group max (stays within head group: masks 1,2,4,8)
    float r = c;
    r = fmaxf(r, __shfl_xor(r, 1));
    r = fmaxf(r, __shfl_xor(r, 2));
    r = fmaxf(r, __shfl_xor(r, 4));
    r = fmaxf(r, __shfl_xor(r, 8));
    const float nm = fmaxf(m, r);
    const float sc = __expf(m - nm);   // first chunk: exp(-inf)=0, acc already 0
#pragma unroll
    for (int t = 0; t < 8; t++) acc[t] *= sc;
    const float p = __expf(c - nm);    // pad lanes -> exactly 0
    float ts = p;
    ts += __shfl_xor(ts, 1);
    ts += __shfl_xor(ts, 2);
    ts += __shfl_xor(ts, 4);
    ts += __shfl_xor(ts, 8);
    d = d * sc + ts;
    m = nm;

    s_p[w][lane] = p;                     // slot (h, j)
    if (lane < 16) s_src[w][lane] = s;    // j-th edge's src (same across head groups)
    __threadfence_block();                // drain ds writes before same-wave reads

    // ---- aggregation over this chunk: batch-4 gathers in flight ----
    const int cnt = (e1 - base) < 16 ? (e1 - base) : 16;
    const int cnt4 = (cnt + 3) & ~3;      // pad slots have p=0, src=0 (L1-hot row 0)
    for (int i = 0; i < cnt4; i += 4) {
      int ss[4]; float ww[4];
#pragma unroll
      for (int q = 0; q < 4; q++) {
        ss[q] = s_src[w][i + q];              // broadcast
        ww[q] = s_p[w][h * 16 + i + q];       // broadcast within head group
      }
      bf16x8 v[4];
#pragma unroll
      for (int q = 0; q < 4; q++)
        v[q] = *(const bf16x8*)(Hb + (size_t)ss[q] * 512 + lane * 8);
#pragma unroll
      for (int q = 0; q < 4; q++)
#pragma unroll
        for (int t = 0; t < 8; t++) acc[t] += ww[q] * (float)v[q][t];
    }
  }

  const float ih = d > 0.f ? 1.0f / d : 0.f;
  bf16x8 o;
#pragma unroll
  for (int t = 0; t < 8; t++) {
    float v = acc[t] * ih + bias[lane * 8 + t];
    v = v > 0.f ? v : expm1f(v);
    o[t] = (bf16_t)v;
  }
  *(bf16x8*)(out + (size_t)n * 512 + lane * 8) = o;
}

// ------------- bf16 MFMA GEMM: C[M][N] = A[M][K] @ Bt[N][K]^T -------------
// 1D grid + XCD-chunked bijective swizzle (col-fastest in chunk -> A-panel L2 reuse)
// EPI=0: store bf16 C.  EPI=1: store fp32 elu(C + bias) (for final FC).
template <int BN, int WM, int WN, int EPI>
__global__ __launch_bounds__(256) void gemm_bt(
    const bf16_t* __restrict__ A, const bf16_t* __restrict__ Bt,
    void* __restrict__ C, const float* __restrict__ bias,
    int M, int N, int K) {
  constexpr int BM = 128, BK = 32;
  constexpr int WTM = BM / WM, WTN = BN / WN;
  constexpr int MF = WTM / 16, NF = WTN / 16;

  __shared__ bf16_t sA[BM][BK];
  __shared__ bf16_t sB[BN][BK];

  const int tid = threadIdx.x;
  const int wid = tid >> 6, lane = tid & 63;
  const int wr = wid / WN, wc = wid % WN;

  // XCD-chunked bijective swizzle (m204)
  const int nby = N / BN;
  const int nwg = gridDim.x;
  const int q = nwg >> 3, r = nwg & 7;
  const int xcd = blockIdx.x & 7, pos = blockIdx.x >> 3;
  const int wg = (xcd < r ? xcd * (q + 1) : r * (q + 1) + (xcd - r) * q) + pos;
  const int row0 = (wg / nby) * BM;
  const int col0 = (wg % nby) * BN;

  f32x4 acc[MF][NF];
#pragma unroll
  for (int i = 0; i < MF; i++)
#pragma unroll
    for (int j = 0; j < NF; j++) acc[i][j] = (f32x4){0.f, 0.f, 0.f, 0.f};

  const int lr = lane >> 2;          // row within 16-row staging group
  const int lkb = (lane & 3) * 8;    // k element offset for staging

  for (int k0 = 0; k0 < K; k0 += BK) {
#pragma unroll
    for (int i = 0; i < BM / 16; i += 4) {
      int r2 = (i + wid) * 16 + lr;
      int grow = row0 + r2; if (grow > M - 1) grow = M - 1;
      gload_lds16(A + (size_t)grow * K + k0 + lkb, &sA[(i + wid) * 16][0]);
    }
#pragma unroll
    for (int i = 0; i < BN / 16; i += 4) {
      int r2 = (i + wid) * 16 + lr;
      gload_lds16(Bt + (size_t)(col0 + r2) * K + k0 + lkb, &sB[(i + wid) * 16][0]);
    }
    __syncthreads();
    bf16x8 af[MF], bfr[NF];
#pragma unroll
    for (int i = 0; i < MF; i++)
      af[i] = *(const bf16x8*)&sA[wr * WTM + i * 16 + (lane & 15)][(lane >> 4) * 8];
#pragma unroll
    for (int j = 0; j < NF; j++)
      bfr[j] = *(const bf16x8*)&sB[wc * WTN + j * 16 + (lane & 15)][(lane >> 4) * 8];
#pragma unroll
    for (int i = 0; i < MF; i++)
#pragma unroll
      for (int j = 0; j < NF; j++)
        acc[i][j] = __builtin_amdgcn_mfma_f32_16x16x32_bf16(af[i], bfr[j], acc[i][j], 0, 0, 0);
    __syncthreads();
  }

#pragma unroll
  for (int i = 0; i < MF; i++) {
#pragma unroll
    for (int j = 0; j < NF; j++) {
#pragma unroll
      for (int rr = 0; rr < 4; rr++) {
        int row = row0 + wr * WTM + i * 16 + (lane >> 4) * 4 + rr;
        int col = col0 + wc * WTN + j * 16 + (lane & 15);
        if (row < M) {
          float v = acc[i][j][rr];
          if constexpr (EPI == 0) {
            ((bf16_t*)C)[(size_t)row * N + col] = (bf16_t)v;
          } else {
            v += bias[col];
            v = v > 0.f ? v : expm1f(v);
            ((float*)C)[(size_t)row * N + col] = v;
          }
        }
      }
    }
  }
}

extern "C" void kernel_launch(void* const* d_in, const int* in_sizes, int n_in,
                              void* d_out, int out_size, void* d_ws, size_t ws_size,
                              hipStream_t stream) {
  const float* feature = (const float*)d_in[0];
  const int* src = (const int*)d_in[1];
  const int* dst = (const int*)d_in[2];
  const float* W1 = (const float*)d_in[3];
  const float* al1 = (const float*)d_in[4];
  const float* ar1 = (const float*)d_in[5];
  const float* b1 = (const float*)d_in[6];
  const float* W2 = (const float*)d_in[7];
  const float* al2 = (const float*)d_in[8];
  const float* ar2 = (const float*)d_in[9];
  const float* b2 = (const float*)d_in[10];
  const float* Wfc = (const float*)d_in[11];
  const float* bfc = (const float*)d_in[12];

  const int N = 20000, E = 320000, INF = 1280, HD = 512;

  char* ws = (char*)d_ws;
  size_t off = 0;
  auto alloc = [&](size_t bytes) {
    void* p = ws + off;
    off += (bytes + 255) & ~(size_t)255;
    return p;
  };
  bf16_t* Xb  = (bf16_t*)alloc((size_t)N * INF * 2);   // 51.2 MB
  bf16_t* W1t = (bf16_t*)alloc((size_t)HD * INF * 2);
  bf16_t* W2t = (bf16_t*)alloc((size_t)HD * HD * 2);
  bf16_t* Wft = (bf16_t*)alloc((size_t)64 * HD * 2);
  bf16_t* Hb  = (bf16_t*)alloc((size_t)N * HD * 2);    // 20.5 MB
  bf16_t* Xn  = (bf16_t*)alloc((size_t)N * HD * 2);    // 20.5 MB
  float* el = (float*)alloc((size_t)N * 4 * 4);
  float* er = (float*)alloc((size_t)N * 4 * 4);
  int* ro = (int*)alloc((size_t)(N + 1) * 4);

  // preprocessing
  castk<<<(N * INF) / (256 * 8), 256, 0, stream>>>(feature, Xb, N * INF);
  {
    dim3 g(HD / 32, INF / 32);
    transk<<<g, 256, 0, stream>>>(W1, W1t, INF, HD);
  }
  {
    dim3 g(HD / 32, HD / 32);
    transk<<<g, 256, 0, stream>>>(W2, W2t, HD, HD);
  }
  {
    dim3 g(64 / 32, HD / 32);
    transk<<<g, 256, 0, stream>>>(Wfc, Wft, HD, 64);
  }
  rowoffk<<<(N + 1 + 255) / 256, 256, 0, stream>>>(dst, ro, N, E);

  const int nbx = (N + 127) / 128;
  const int aggBlocks = (N + AGG_WAVES - 1) / AGG_WAVES;

  // layer 1
  gemm_bt<128, 2, 2, 0><<<nbx * (HD / 128), 256, 0, stream>>>(Xb, W1t, Hb, nullptr, N, HD, INF);
  elerk<<<N / 4, 256, 0, stream>>>(Hb, al1, ar1, el, er, N);
  aggk<<<aggBlocks, 256, 0, stream>>>(Hb, el, er, src, ro, b1, Xn, N);

  // layer 2
  gemm_bt<128, 2, 2, 0><<<nbx * (HD / 128), 256, 0, stream>>>(Xn, W2t, Hb, nullptr, N, HD, HD);
  elerk<<<N / 4, 256, 0, stream>>>(Hb, al2, ar2, el, er, N);
  aggk<<<aggBlocks, 256, 0, stream>>>(Hb, el, er, src, ro, b2, Xn, N);

  // final FC + elu -> d_out (fp32)
  gemm_bt<64, 4, 1, 1><<<nbx, 256, 0, stream>>>(Xn, Wft, d_out, bfc, N, 64, HD);
}